// Round 8
// baseline (379.970 us; speedup 1.0000x reference)
//
#include <hip/hip_runtime.h>
#include <hip/hip_bf16.h>
#include <cstdint>
#include <cstddef>

#define HIDDEN 256
#define NHEADS 8
#define HDIM 32
#define KLEN 8192
#define BATCH 32
#define NCHUNK 16
#define CHUNK (KLEN / NCHUNK)     // 512
#define NSLAB 32                  // scores slabs per (m,b)
#define LN_EPS 1e-5f

typedef __attribute__((ext_vector_type(4))) unsigned short u16x4;

// ---------------- workspace layout (float offsets) ----------------
#define OFF_QT    ((size_t)0)
#define SZ_QT     ((size_t)2*BATCH*NHEADS*HIDDEN)           // 131072
#define OFF_SC    (OFF_QT + SZ_QT)
#define SZ_SC     ((size_t)2*BATCH*KLEN*NHEADS)             // 4194304 (z, [mb][n][k])
#define OFF_PT    (OFF_SC + SZ_SC)
#define SZ_PT     ((size_t)2*BATCH*KLEN*NHEADS)             // 4194304 (p, [mb][k][n])
#define OFF_UP    (OFF_PT + SZ_PT)
#define SZ_UP     ((size_t)2*BATCH*NCHUNK*NHEADS*HIDDEN)    // 2097152
#define OFF_COMB  (OFF_UP + SZ_UP)
#define SZ_COMB   ((size_t)BATCH*2*HIDDEN)                  // 16384
#define OFF_KVB_BYTES ((OFF_COMB + SZ_COMB) * 4)            // 16B aligned
#define SZ_KVB_BYTES  ((size_t)2*BATCH*KLEN*HIDDEN*2)       // 268435456 (bf16 kv cache)
#define WS_NEEDED     (OFF_KVB_BYTES + SZ_KVB_BYTES)

static __device__ inline unsigned short f2bu(float f) {
    __hip_bfloat16 h = __float2bfloat16(f);
    return __builtin_bit_cast(unsigned short, h);
}
static __device__ inline float b2f(unsigned short s) {
    unsigned u = ((unsigned)s) << 16;
    return __builtin_bit_cast(float, u);
}

// K1: qh = z_gene @ Wq^T, then qtilde[m][b][n][h] = alpha * sum_d qh[n,d]*Wk_m[n*32+d, h]
__global__ void k_prep(const float* __restrict__ zg, const float* __restrict__ Wq,
                       const float* __restrict__ Wk0, const float* __restrict__ Wk1,
                       const float* __restrict__ log_temp, float* __restrict__ qt) {
    int b = blockIdx.x, t = threadIdx.x;
    __shared__ float z[HIDDEN];
    __shared__ float qh[HIDDEN];
    z[t] = zg[(size_t)b*HIDDEN + t];
    __syncthreads();
    const float4* wr4 = (const float4*)(Wq + (size_t)t*HIDDEN);
    const float4* z4 = (const float4*)z;
    float acc = 0.f;
    #pragma unroll 8
    for (int i = 0; i < HIDDEN/4; ++i) {
        float4 w = wr4[i], zz = z4[i];
        acc += w.x*zz.x + w.y*zz.y + w.z*zz.z + w.w*zz.w;
    }
    qh[t] = acc;
    __syncthreads();
    float alpha = 0.5f * rsqrtf((float)HDIM) * __expf(log_temp[0]);
    for (int m = 0; m < 2; ++m) {
        const float* Wk = m ? Wk1 : Wk0;
        for (int n = 0; n < NHEADS; ++n) {
            float a = 0.f;
            #pragma unroll 8
            for (int d = 0; d < HDIM; ++d) {
                a += qh[n*HDIM + d] * Wk[(size_t)(n*HDIM + d)*HIDDEN + t];
            }
            qt[(((size_t)m*BATCH + b)*NHEADS + n)*HIDDEN + t] = a * alpha;
        }
    }
}

// K2 v8: wave-contiguous scores (at the read wall) + bf16 kv cache write (write
// direction, ~free under full-duplex) + LDS transpose so sc is [mb][n][k].
__global__ void __launch_bounds__(256, 4) k_scores(const float* __restrict__ kv0,
                                                   const float* __restrict__ kv1,
                                                   const float* __restrict__ qt,
                                                   float* __restrict__ sc,
                                                   unsigned short* __restrict__ kvb,
                                                   int do_cache) {
    int bid = blockIdx.x;              // mb*NSLAB + slab, 64*32 = 2048
    int slab = bid & (NSLAB - 1);
    int mb = bid / NSLAB;              // m*32+b
    int t = threadIdx.x;
    int wave = t >> 6, l = t & 63;
    const float* kv = ((mb >> 5) ? kv1 : kv0) + (size_t)(mb & 31)*KLEN*HIDDEN;
    const float4* kv4 = (const float4*)kv;
    unsigned short* kvbm = kvb + (size_t)mb*KLEN*HIDDEN;
    const float* qtg = qt + (size_t)mb*NHEADS*HIDDEN;
    float4 qreg[8];
    #pragma unroll
    for (int n = 0; n < 8; ++n)
        qreg[n] = *(const float4*)(qtg + (size_t)n*HIDDEN + 4*l);
    __shared__ float ls[NHEADS][260];  // transpose buffer (pad 260: banks (4n+k)%32)
    int b0 = l & 1, b1 = (l >> 1) & 1, b2 = (l >> 2) & 1;

    int k = slab*256 + wave;
    float4 cur = kv4[(size_t)k*64 + l];
    #pragma unroll 2
    for (int i = 0; i < 64; ++i) {
        float4 nxt = cur;
        if (i < 63) nxt = kv4[(size_t)(k + 4)*64 + l];
        if (do_cache) {
            u16x4 bv;
            bv[0] = f2bu(cur.x); bv[1] = f2bu(cur.y);
            bv[2] = f2bu(cur.z); bv[3] = f2bu(cur.w);
            *(u16x4*)(kvbm + (size_t)k*HIDDEN + 4*l) = bv;
        }
        float a[8];
        #pragma unroll
        for (int n = 0; n < 8; ++n)
            a[n] = cur.x*qreg[n].x + cur.y*qreg[n].y + cur.z*qreg[n].z + cur.w*qreg[n].w;
        // transposing butterfly: after xor 1,2,4 lane holds head (l&7) partial
        float w[4];
        #pragma unroll
        for (int u = 0; u < 4; ++u) {
            float keep = b0 ? a[2*u+1] : a[2*u];
            float send = b0 ? a[2*u]   : a[2*u+1];
            w[u] = keep + __shfl_xor(send, 1);
        }
        float x[2];
        #pragma unroll
        for (int u = 0; u < 2; ++u) {
            float keep = b1 ? w[2*u+1] : w[2*u];
            float send = b1 ? w[2*u]   : w[2*u+1];
            x[u] = keep + __shfl_xor(send, 2);
        }
        float keep = b2 ? x[1] : x[0];
        float send = b2 ? x[0] : x[1];
        float y = keep + __shfl_xor(send, 4);
        y += __shfl_xor(y, 8);
        y += __shfl_xor(y, 16);
        y += __shfl_xor(y, 32);
        if (l < 8) ls[l][k - slab*256] = y;
        cur = nxt; k += 4;
    }
    __syncthreads();
    // coalesced transposed write-out: sc[mb][n][slab*256 + j]
    float* outb = sc + (size_t)mb*NHEADS*KLEN + slab*256;
    int n = t >> 5, j0 = (t & 31)*8;
    float4 v0 = *(const float4*)&ls[n][j0];
    float4 v1 = *(const float4*)&ls[n][j0 + 4];
    *(float4*)(outb + (size_t)n*KLEN + j0)     = v0;
    *(float4*)(outb + (size_t)n*KLEN + j0 + 4) = v1;
}

// K3 v5: entmax on contiguous [n][k] rows; writes p to pT in [k][n] order.
__global__ void __launch_bounds__(256) k_entmax(const float* __restrict__ sc,
                                                float* __restrict__ pT) {
    int bid = blockIdx.x;              // mb*8 + n
    int n = bid & 7;
    int mb = bid >> 3;
    int t = threadIdx.x;
    __shared__ float zs[KLEN];
    __shared__ float red[4];
    const float4* s4 = (const float4*)(sc + (size_t)bid*KLEN);
    float4* z4w = (float4*)zs;
    float mx = -1e30f;
    #pragma unroll
    for (int i = 0; i < 8; ++i) {
        float4 v = s4[t + i*256];
        z4w[t + i*256] = v;
        mx = fmaxf(fmaxf(fmaxf(mx, v.x), v.y), fmaxf(v.z, v.w));
    }
    for (int off = 32; off; off >>= 1) mx = fmaxf(mx, __shfl_xor(mx, off));
    if ((t & 63) == 0) red[t >> 6] = mx;
    __syncthreads();
    mx = fmaxf(fmaxf(red[0], red[1]), fmaxf(red[2], red[3]));
    __syncthreads();
    const float4* z4 = (const float4*)zs;
    float lo = mx - 1.0f, hi = mx;
    for (int it = 0; it < 22; ++it) {
        float tm = 0.5f*(lo + hi);
        float s = 0.f;
        #pragma unroll
        for (int i = 0; i < 8; ++i) {
            float4 zz = z4[t + i*256];
            float d;
            d = fmaxf(zz.x - tm, 0.f); s = fmaf(d, d, s);
            d = fmaxf(zz.y - tm, 0.f); s = fmaf(d, d, s);
            d = fmaxf(zz.z - tm, 0.f); s = fmaf(d, d, s);
            d = fmaxf(zz.w - tm, 0.f); s = fmaf(d, d, s);
        }
        for (int off = 32; off; off >>= 1) s += __shfl_xor(s, off);
        if ((t & 63) == 0) red[t >> 6] = s;
        __syncthreads();
        s = red[0] + red[1] + red[2] + red[3];
        __syncthreads();
        if (s >= 1.0f) lo = tm; else hi = tm;
    }
    float tfin = 0.5f*(lo + hi);
    float* pTm = pT + (size_t)mb*KLEN*NHEADS + n;
    #pragma unroll
    for (int i = 0; i < 8; ++i) {
        float4 zz = z4[t + i*256];
        int k = (t + i*256)*4;
        float d;
        d = fmaxf(zz.x - tfin, 0.f); pTm[(size_t)(k+0)*NHEADS] = d*d;
        d = fmaxf(zz.y - tfin, 0.f); pTm[(size_t)(k+1)*NHEADS] = d*d;
        d = fmaxf(zz.z - tfin, 0.f); pTm[(size_t)(k+2)*NHEADS] = d*d;
        d = fmaxf(zz.w - tfin, 0.f); pTm[(size_t)(k+3)*NHEADS] = d*d;
    }
}

// K4 v9 (fast path): R2's proven ctxsum structure, kv from the bf16 cache
// (284 MB read instead of 553 MB). p rows uniform 32 B as in R2.
__global__ void __launch_bounds__(256, 4) k_ctxsum_bf(const unsigned short* __restrict__ kvb,
                                                      const float* __restrict__ pT,
                                                      float* __restrict__ upart) {
    int bid = blockIdx.x;              // mb*NCHUNK + chunk, 1024
    int chunk = bid % NCHUNK;
    int mb = bid / NCHUNK;
    int t = threadIdx.x;
    int wave = t >> 6, lane = t & 63;
    const unsigned short* kvm = kvb + (size_t)mb*KLEN*HIDDEN;
    const float4* prow4 = (const float4*)(pT + (size_t)mb*KLEN*NHEADS);
    float acc[8][4];
    #pragma unroll
    for (int n = 0; n < 8; ++n)
        #pragma unroll
        for (int c = 0; c < 4; ++c) acc[n][c] = 0.f;

    #pragma unroll 2
    for (int kk = wave; kk < CHUNK; kk += 4) {
        size_t k = (size_t)chunk*CHUNK + kk;
        u16x4 kvv = *(const u16x4*)(kvm + k*HIDDEN + 4*lane);
        float kx = b2f(kvv[0]), ky = b2f(kvv[1]), kz = b2f(kvv[2]), kw = b2f(kvv[3]);
        float4 p0 = prow4[k*2], p1 = prow4[k*2 + 1];
        acc[0][0] = fmaf(p0.x, kx, acc[0][0]); acc[0][1] = fmaf(p0.x, ky, acc[0][1]);
        acc[0][2] = fmaf(p0.x, kz, acc[0][2]); acc[0][3] = fmaf(p0.x, kw, acc[0][3]);
        acc[1][0] = fmaf(p0.y, kx, acc[1][0]); acc[1][1] = fmaf(p0.y, ky, acc[1][1]);
        acc[1][2] = fmaf(p0.y, kz, acc[1][2]); acc[1][3] = fmaf(p0.y, kw, acc[1][3]);
        acc[2][0] = fmaf(p0.z, kx, acc[2][0]); acc[2][1] = fmaf(p0.z, ky, acc[2][1]);
        acc[2][2] = fmaf(p0.z, kz, acc[2][2]); acc[2][3] = fmaf(p0.z, kw, acc[2][3]);
        acc[3][0] = fmaf(p0.w, kx, acc[3][0]); acc[3][1] = fmaf(p0.w, ky, acc[3][1]);
        acc[3][2] = fmaf(p0.w, kz, acc[3][2]); acc[3][3] = fmaf(p0.w, kw, acc[3][3]);
        acc[4][0] = fmaf(p1.x, kx, acc[4][0]); acc[4][1] = fmaf(p1.x, ky, acc[4][1]);
        acc[4][2] = fmaf(p1.x, kz, acc[4][2]); acc[4][3] = fmaf(p1.x, kw, acc[4][3]);
        acc[5][0] = fmaf(p1.y, kx, acc[5][0]); acc[5][1] = fmaf(p1.y, ky, acc[5][1]);
        acc[5][2] = fmaf(p1.y, kz, acc[5][2]); acc[5][3] = fmaf(p1.y, kw, acc[5][3]);
        acc[6][0] = fmaf(p1.z, kx, acc[6][0]); acc[6][1] = fmaf(p1.z, ky, acc[6][1]);
        acc[6][2] = fmaf(p1.z, kz, acc[6][2]); acc[6][3] = fmaf(p1.z, kw, acc[6][3]);
        acc[7][0] = fmaf(p1.w, kx, acc[7][0]); acc[7][1] = fmaf(p1.w, ky, acc[7][1]);
        acc[7][2] = fmaf(p1.w, kz, acc[7][2]); acc[7][3] = fmaf(p1.w, kw, acc[7][3]);
    }
    __shared__ float redls[4*NHEADS*HIDDEN];    // 32 KB
    float4* red4 = (float4*)redls;
    #pragma unroll
    for (int n = 0; n < 8; ++n) {
        float4 v; v.x = acc[n][0]; v.y = acc[n][1]; v.z = acc[n][2]; v.w = acc[n][3];
        red4[((size_t)wave*8 + n)*64 + lane] = v;
    }
    __syncthreads();
    float* up = upart + ((size_t)mb*NCHUNK + chunk)*NHEADS*HIDDEN;
    int n = t >> 5, hq = (t & 31)*2;
    #pragma unroll
    for (int j = 0; j < 2; ++j) {
        float4 s = red4[((size_t)0*8 + n)*64 + hq + j];
        #pragma unroll
        for (int w = 1; w < 4; ++w) {
            float4 v = red4[((size_t)w*8 + n)*64 + hq + j];
            s.x += v.x; s.y += v.y; s.z += v.z; s.w += v.w;
        }
        ((float4*)(up + (size_t)n*HIDDEN))[hq + j] = s;
    }
}

// K4 fallback (ws too small): same structure, fp32 kv.
__global__ void __launch_bounds__(256, 4) k_ctxsum_f32(const float* __restrict__ kv0,
                                                       const float* __restrict__ kv1,
                                                       const float* __restrict__ pT,
                                                       float* __restrict__ upart) {
    int bid = blockIdx.x;
    int chunk = bid % NCHUNK;
    int mb = bid / NCHUNK;
    int t = threadIdx.x;
    int wave = t >> 6, lane = t & 63;
    const float* kv = ((mb >> 5) ? kv1 : kv0) + (size_t)(mb & 31)*KLEN*HIDDEN;
    const float4* kv4 = (const float4*)kv;
    const float4* prow4 = (const float4*)(pT + (size_t)mb*KLEN*NHEADS);
    float acc[8][4];
    #pragma unroll
    for (int n = 0; n < 8; ++n)
        #pragma unroll
        for (int c = 0; c < 4; ++c) acc[n][c] = 0.f;
    #pragma unroll 2
    for (int kk = wave; kk < CHUNK; kk += 4) {
        size_t k = (size_t)chunk*CHUNK + kk;
        float4 kvv = kv4[k*64 + lane];
        float kx = kvv.x, ky = kvv.y, kz = kvv.z, kw = kvv.w;
        float4 p0 = prow4[k*2], p1 = prow4[k*2 + 1];
        acc[0][0] = fmaf(p0.x, kx, acc[0][0]); acc[0][1] = fmaf(p0.x, ky, acc[0][1]);
        acc[0][2] = fmaf(p0.x, kz, acc[0][2]); acc[0][3] = fmaf(p0.x, kw, acc[0][3]);
        acc[1][0] = fmaf(p0.y, kx, acc[1][0]); acc[1][1] = fmaf(p0.y, ky, acc[1][1]);
        acc[1][2] = fmaf(p0.y, kz, acc[1][2]); acc[1][3] = fmaf(p0.y, kw, acc[1][3]);
        acc[2][0] = fmaf(p0.z, kx, acc[2][0]); acc[2][1] = fmaf(p0.z, ky, acc[2][1]);
        acc[2][2] = fmaf(p0.z, kz, acc[2][2]); acc[2][3] = fmaf(p0.z, kw, acc[2][3]);
        acc[3][0] = fmaf(p0.w, kx, acc[3][0]); acc[3][1] = fmaf(p0.w, ky, acc[3][1]);
        acc[3][2] = fmaf(p0.w, kz, acc[3][2]); acc[3][3] = fmaf(p0.w, kw, acc[3][3]);
        acc[4][0] = fmaf(p1.x, kx, acc[4][0]); acc[4][1] = fmaf(p1.x, ky, acc[4][1]);
        acc[4][2] = fmaf(p1.x, kz, acc[4][2]); acc[4][3] = fmaf(p1.x, kw, acc[4][3]);
        acc[5][0] = fmaf(p1.y, kx, acc[5][0]); acc[5][1] = fmaf(p1.y, ky, acc[5][1]);
        acc[5][2] = fmaf(p1.y, kz, acc[5][2]); acc[5][3] = fmaf(p1.y, kw, acc[5][3]);
        acc[6][0] = fmaf(p1.z, kx, acc[6][0]); acc[6][1] = fmaf(p1.z, ky, acc[6][1]);
        acc[6][2] = fmaf(p1.z, kz, acc[6][2]); acc[6][3] = fmaf(p1.z, kw, acc[6][3]);
        acc[7][0] = fmaf(p1.w, kx, acc[7][0]); acc[7][1] = fmaf(p1.w, ky, acc[7][1]);
        acc[7][2] = fmaf(p1.w, kz, acc[7][2]); acc[7][3] = fmaf(p1.w, kw, acc[7][3]);
    }
    __shared__ float redls[4*NHEADS*HIDDEN];
    float4* red4 = (float4*)redls;
    #pragma unroll
    for (int n = 0; n < 8; ++n) {
        float4 v; v.x = acc[n][0]; v.y = acc[n][1]; v.z = acc[n][2]; v.w = acc[n][3];
        red4[((size_t)wave*8 + n)*64 + lane] = v;
    }
    __syncthreads();
    float* up = upart + ((size_t)mb*NCHUNK + chunk)*NHEADS*HIDDEN;
    int n = t >> 5, hq = (t & 31)*2;
    #pragma unroll
    for (int j = 0; j < 2; ++j) {
        float4 s = red4[((size_t)0*8 + n)*64 + hq + j];
        #pragma unroll
        for (int w = 1; w < 4; ++w) {
            float4 v = red4[((size_t)w*8 + n)*64 + hq + j];
            s.x += v.x; s.y += v.y; s.z += v.z; s.w += v.w;
        }
        ((float4*)(up + (size_t)n*HIDDEN))[hq + j] = s;
    }
}

// K5: reduce chunks, project through Wv, apply modality softmax weight
__global__ void k_ctx(const float* __restrict__ upart, const float* __restrict__ Wv0,
                      const float* __restrict__ Wv1, const float* __restrict__ mlogits,
                      float* __restrict__ comb) {
    int b = blockIdx.x, t = threadIdx.x;
    __shared__ float ul[NHEADS*260];
    float l0 = mlogits[0], l1 = mlogits[1];
    float mxl = fmaxf(l0, l1);
    float e0 = __expf(l0 - mxl), e1 = __expf(l1 - mxl);
    float w0 = e0/(e0 + e1), w1 = e1/(e0 + e1);
    for (int m = 0; m < 2; ++m) {
        const float* Wv = m ? Wv1 : Wv0;
        float wm = m ? w1 : w0;
        __syncthreads();
        for (int n = 0; n < NHEADS; ++n) {
            float s = 0.f;
            const float* up = upart + ((size_t)m*BATCH + b)*NCHUNK*NHEADS*HIDDEN
                              + (size_t)n*HIDDEN + t;
            #pragma unroll
            for (int c = 0; c < NCHUNK; ++c) s += up[(size_t)c*NHEADS*HIDDEN];
            ul[n*260 + t] = s;
        }
        __syncthreads();
        int n = t >> 5;   // t = n*32 + d
        const float4* wr4 = (const float4*)(Wv + (size_t)t*HIDDEN);
        const float4* uu4 = (const float4*)(ul + n*260);
        float acc = 0.f;
        #pragma unroll 8
        for (int i = 0; i < HIDDEN/4; ++i) {
            float4 w = wr4[i], uu = uu4[i];
            acc += w.x*uu.x + w.y*uu.y + w.z*uu.z + w.w*uu.w;
        }
        comb[(size_t)b*(2*HIDDEN) + (size_t)m*HIDDEN + t] = acc * wm;
    }
}

// K6: out = LayerNorm(comb @ Wout^T + b_out + z_gene)
__global__ void k_out(const float* __restrict__ comb, const float* __restrict__ Wout,
                      const float* __restrict__ bout, const float* __restrict__ zg,
                      const float* __restrict__ gamma, const float* __restrict__ beta,
                      float* __restrict__ out) {
    int b = blockIdx.x, t = threadIdx.x;
    __shared__ float cl[2*HIDDEN];
    __shared__ float red[4];
    cl[t] = comb[(size_t)b*512 + t];
    cl[t + 256] = comb[(size_t)b*512 + 256 + t];
    __syncthreads();
    float acc = bout[t] + zg[(size_t)b*HIDDEN + t];
    const float4* wr4 = (const float4*)(Wout + (size_t)t*512);
    const float4* cl4 = (const float4*)cl;
    #pragma unroll 8
    for (int i = 0; i < 512/4; ++i) {
        float4 w = wr4[i], c = cl4[i];
        acc += w.x*c.x + w.y*c.y + w.z*c.z + w.w*c.w;
    }
    float s = acc;
    for (int off = 32; off; off >>= 1) s += __shfl_xor(s, off);
    if ((t & 63) == 0) red[t >> 6] = s;
    __syncthreads();
    float mu = (red[0] + red[1] + red[2] + red[3]) * (1.0f/HIDDEN);
    __syncthreads();
    float dv = acc - mu;
    float vs = dv*dv;
    for (int off = 32; off; off >>= 1) vs += __shfl_xor(vs, off);
    if ((t & 63) == 0) red[t >> 6] = vs;
    __syncthreads();
    float var = (red[0] + red[1] + red[2] + red[3]) * (1.0f/HIDDEN);
    out[(size_t)b*HIDDEN + t] = dv * rsqrtf(var + LN_EPS) * gamma[t] + beta[t];
}

extern "C" void kernel_launch(void* const* d_in, const int* in_sizes, int n_in,
                              void* d_out, int out_size, void* d_ws, size_t ws_size,
                              hipStream_t stream) {
    const float* zg    = (const float*)d_in[0];
    const float* cpg   = (const float*)d_in[1];
    const float* mir   = (const float*)d_in[2];
    const float* Wq    = (const float*)d_in[3];
    const float* Wk0   = (const float*)d_in[4];
    const float* Wv0   = (const float*)d_in[5];
    const float* Wk1   = (const float*)d_in[6];
    const float* Wv1   = (const float*)d_in[7];
    const float* Wout  = (const float*)d_in[8];
    const float* bout  = (const float*)d_in[9];
    const float* gam   = (const float*)d_in[10];
    const float* bet   = (const float*)d_in[11];
    const float* mlog  = (const float*)d_in[12];
    const float* ltemp = (const float*)d_in[13];

    float* ws    = (float*)d_ws;
    float* qt    = ws + OFF_QT;
    float* sc    = ws + OFF_SC;
    float* pT    = ws + OFF_PT;
    float* up    = ws + OFF_UP;
    float* comb  = ws + OFF_COMB;
    unsigned short* kvb = (unsigned short*)((char*)d_ws + OFF_KVB_BYTES);
    float* out   = (float*)d_out;

    int do_cache = (ws_size >= (size_t)WS_NEEDED) ? 1 : 0;

    hipLaunchKernelGGL(k_prep,   dim3(BATCH),           dim3(256), 0, stream,
                       zg, Wq, Wk0, Wk1, ltemp, qt);
    hipLaunchKernelGGL(k_scores, dim3(2*BATCH*NSLAB),   dim3(256), 0, stream,
                       cpg, mir, qt, sc, kvb, do_cache);
    hipLaunchKernelGGL(k_entmax, dim3(2*BATCH*NHEADS),  dim3(256), 0, stream,
                       sc, pT);
    if (do_cache) {
        hipLaunchKernelGGL(k_ctxsum_bf, dim3(2*BATCH*NCHUNK), dim3(256), 0, stream,
                           kvb, pT, up);
    } else {
        hipLaunchKernelGGL(k_ctxsum_f32, dim3(2*BATCH*NCHUNK), dim3(256), 0, stream,
                           cpg, mir, pT, up);
    }
    hipLaunchKernelGGL(k_ctx,    dim3(BATCH),           dim3(256), 0, stream,
                       up, Wv0, Wv1, mlog, comb);
    hipLaunchKernelGGL(k_out,    dim3(BATCH),           dim3(256), 0, stream,
                       comb, Wout, bout, zg, gam, bet, out);
}

// Round 9
// 322.054 us; speedup vs baseline: 1.1798x; 1.1798x over previous
//
#include <hip/hip_runtime.h>
#include <cstdint>
#include <cstddef>

#define HIDDEN 256
#define NHEADS 8
#define HDIM 32
#define KLEN 8192
#define BATCH 32
#define NCHUNK 16
#define CHUNK (KLEN / NCHUNK)     // 512
#define NSLAB 32                  // scores slabs per (m,b)
#define LN_EPS 1e-5f

// ---------------- workspace layout (float offsets) ----------------
#define OFF_QT    ((size_t)0)
#define SZ_QT     ((size_t)2*BATCH*NHEADS*HIDDEN)           // 131072
#define OFF_SC    (OFF_QT + SZ_QT)
#define SZ_SC     ((size_t)2*BATCH*KLEN*NHEADS)             // 4194304 (z, [mb][k][n])
#define OFF_TAU   (OFF_SC + SZ_SC)
#define SZ_TAU    ((size_t)2*BATCH*NHEADS)                  // 512
#define OFF_UP    (OFF_TAU + SZ_TAU)
#define SZ_UP     ((size_t)2*BATCH*NCHUNK*NHEADS*HIDDEN)    // 2097152
#define OFF_COMB  (OFF_UP + SZ_UP)
#define SZ_COMB   ((size_t)BATCH*2*HIDDEN)                  // 16384

// K1: qh = z_gene @ Wq^T, then qtilde[m][b][n][h] = alpha * sum_d qh[n,d]*Wk_m[n*32+d, h]
__global__ void k_prep(const float* __restrict__ zg, const float* __restrict__ Wq,
                       const float* __restrict__ Wk0, const float* __restrict__ Wk1,
                       const float* __restrict__ log_temp, float* __restrict__ qt) {
    int b = blockIdx.x, t = threadIdx.x;
    __shared__ float z[HIDDEN];
    __shared__ float qh[HIDDEN];
    z[t] = zg[(size_t)b*HIDDEN + t];
    __syncthreads();
    const float4* wr4 = (const float4*)(Wq + (size_t)t*HIDDEN);
    const float4* z4 = (const float4*)z;
    float acc = 0.f;
    #pragma unroll 8
    for (int i = 0; i < HIDDEN/4; ++i) {
        float4 w = wr4[i], zz = z4[i];
        acc += w.x*zz.x + w.y*zz.y + w.z*zz.z + w.w*zz.w;
    }
    qh[t] = acc;
    __syncthreads();
    float alpha = 0.5f * rsqrtf((float)HDIM) * __expf(log_temp[0]);
    for (int m = 0; m < 2; ++m) {
        const float* Wk = m ? Wk1 : Wk0;
        for (int n = 0; n < NHEADS; ++n) {
            float a = 0.f;
            #pragma unroll 8
            for (int d = 0; d < HDIM; ++d) {
                a += qh[n*HDIM + d] * Wk[(size_t)(n*HDIM + d)*HIDDEN + t];
            }
            qt[(((size_t)m*BATCH + b)*NHEADS + n)*HIDDEN + t] = a * alpha;
        }
    }
}

// K2 (R7's measured-best, 163 us): wave-contiguous scores. One kv row per
// wave-iteration: lane l reads kv4[k*64+l] (1 KB contiguous per wave instr).
// q-tilde preloaded in 32 VGPRs. 32 FMA -> transposing shfl butterfly ->
// lanes 0..7 hold the 8 head scores -> 32 B store per row. Only 16 MB written.
__global__ void __launch_bounds__(256, 4) k_scores(const float* __restrict__ kv0,
                                                   const float* __restrict__ kv1,
                                                   const float* __restrict__ qt,
                                                   float* __restrict__ sc) {
    int bid = blockIdx.x;              // mb*NSLAB + slab, 64*32 = 2048
    int slab = bid & (NSLAB - 1);
    int mb = bid / NSLAB;              // m*32+b
    int t = threadIdx.x;
    int wave = t >> 6, l = t & 63;
    const float* kv = ((mb >> 5) ? kv1 : kv0) + (size_t)(mb & 31)*KLEN*HIDDEN;
    const float4* kv4 = (const float4*)kv;
    const float* qtg = qt + (size_t)mb*NHEADS*HIDDEN;
    float4 qreg[8];
    #pragma unroll
    for (int n = 0; n < 8; ++n)
        qreg[n] = *(const float4*)(qtg + (size_t)n*HIDDEN + 4*l);
    float* out = sc + (size_t)mb*KLEN*NHEADS;
    int b0 = l & 1, b1 = (l >> 1) & 1, b2 = (l >> 2) & 1;

    int k = slab*256 + wave;
    float4 cur = kv4[(size_t)k*64 + l];
    #pragma unroll 2
    for (int i = 0; i < 64; ++i) {
        float4 nxt = cur;
        if (i < 63) nxt = kv4[(size_t)(k + 4)*64 + l];
        float a[8];
        #pragma unroll
        for (int n = 0; n < 8; ++n)
            a[n] = cur.x*qreg[n].x + cur.y*qreg[n].y + cur.z*qreg[n].z + cur.w*qreg[n].w;
        float w[4];
        #pragma unroll
        for (int u = 0; u < 4; ++u) {
            float keep = b0 ? a[2*u+1] : a[2*u];
            float send = b0 ? a[2*u]   : a[2*u+1];
            w[u] = keep + __shfl_xor(send, 1);
        }
        float x[2];
        #pragma unroll
        for (int u = 0; u < 2; ++u) {
            float keep = b1 ? w[2*u+1] : w[2*u];
            float send = b1 ? w[2*u]   : w[2*u+1];
            x[u] = keep + __shfl_xor(send, 2);
        }
        float keep = b2 ? x[1] : x[0];
        float send = b2 ? x[0] : x[1];
        float y = keep + __shfl_xor(send, 4);
        y += __shfl_xor(y, 8);
        y += __shfl_xor(y, 16);
        y += __shfl_xor(y, 32);
        if (l < 8) out[(size_t)k*8 + l] = y;
        cur = nxt; k += 4;
    }
}

// K3 (Newton): solve g(tau) = sum max(z-tau,0)^2 = 1. g convex decreasing,
// g(mx-1) >= 1 (max element alone contributes 1), so Newton from tau0 = mx-1
// converges monotonically from below (tangent underestimates convex g).
// 10 fixed iterations >> bisection's 26 passes. Writes tau only (no p rewrite).
__global__ void __launch_bounds__(256) k_entmax(const float* __restrict__ sc,
                                                float* __restrict__ tau) {
    int bid = blockIdx.x;              // mb*8 + n, 512 blocks
    int n = bid & 7;
    int mb = bid >> 3;
    int t = threadIdx.x;
    __shared__ float zs[KLEN];
    __shared__ float redg[4];
    __shared__ float redd[4];
    const float* src = sc + (size_t)mb*KLEN*NHEADS + n;
    float mx = -1e30f;
    #pragma unroll
    for (int i = 0; i < KLEN/256; ++i) {
        float v = src[(size_t)(t + i*256)*NHEADS];
        zs[t + i*256] = v;
        mx = fmaxf(mx, v);
    }
    for (int off = 32; off; off >>= 1) mx = fmaxf(mx, __shfl_xor(mx, off));
    if ((t & 63) == 0) redg[t >> 6] = mx;
    __syncthreads();
    mx = fmaxf(fmaxf(redg[0], redg[1]), fmaxf(redg[2], redg[3]));
    __syncthreads();
    const float4* z4 = (const float4*)zs;
    float tk = mx - 1.0f;
    for (int it = 0; it < 10; ++it) {
        float g = 0.f, gd = 0.f;
        #pragma unroll
        for (int i = 0; i < 8; ++i) {
            float4 zz = z4[t + i*256];
            float d;
            d = fmaxf(zz.x - tk, 0.f); g = fmaf(d, d, g); gd += d;
            d = fmaxf(zz.y - tk, 0.f); g = fmaf(d, d, g); gd += d;
            d = fmaxf(zz.z - tk, 0.f); g = fmaf(d, d, g); gd += d;
            d = fmaxf(zz.w - tk, 0.f); g = fmaf(d, d, g); gd += d;
        }
        for (int off = 32; off; off >>= 1) {
            g  += __shfl_xor(g, off);
            gd += __shfl_xor(gd, off);
        }
        if ((t & 63) == 0) { redg[t >> 6] = g; redd[t >> 6] = gd; }
        __syncthreads();
        g  = redg[0] + redg[1] + redg[2] + redg[3];
        gd = redd[0] + redd[1] + redd[2] + redd[3];
        __syncthreads();
        float denom = fmaxf(2.f*gd, 1e-12f);
        tk = fminf(tk + (g - 1.0f)/denom, mx);   // Newton step toward g=1
    }
    if (t == 0) tau[bid] = tk;
}

// K4 (R2's proven 104us structure): wave-contiguous kv row per iteration,
// uniform 32 B z loads, p = max(z-tau,0)^2 computed inline (8 VALU), 32 FMA.
__global__ void __launch_bounds__(256) k_ctxsum(const float* __restrict__ kv0,
                                                const float* __restrict__ kv1,
                                                const float* __restrict__ sc,
                                                const float* __restrict__ tau,
                                                float* __restrict__ upart) {
    int bid = blockIdx.x;              // mb*NCHUNK + chunk, 1024
    int chunk = bid % NCHUNK;
    int mb = bid / NCHUNK;             // m*32+b
    int t = threadIdx.x;
    int wave = t >> 6, lane = t & 63;
    const float* kv = ((mb >> 5) ? kv1 : kv0) + (size_t)(mb & 31)*KLEN*HIDDEN;
    const float4* kv4 = (const float4*)kv;
    const float4* zrow4 = (const float4*)(sc + (size_t)mb*KLEN*NHEADS);
    float tv[8];
    #pragma unroll
    for (int n = 0; n < 8; ++n) tv[n] = tau[(size_t)mb*NHEADS + n];
    float acc[8][4];
    #pragma unroll
    for (int n = 0; n < 8; ++n)
        #pragma unroll
        for (int c = 0; c < 4; ++c) acc[n][c] = 0.f;

    #pragma unroll 2
    for (int kk = wave; kk < CHUNK; kk += 4) {
        size_t k = (size_t)chunk*CHUNK + kk;
        float4 kvv = kv4[k*64 + lane];
        float4 za = zrow4[k*2], zb = zrow4[k*2 + 1];
        float p[8], d;
        d = fmaxf(za.x - tv[0], 0.f); p[0] = d*d;
        d = fmaxf(za.y - tv[1], 0.f); p[1] = d*d;
        d = fmaxf(za.z - tv[2], 0.f); p[2] = d*d;
        d = fmaxf(za.w - tv[3], 0.f); p[3] = d*d;
        d = fmaxf(zb.x - tv[4], 0.f); p[4] = d*d;
        d = fmaxf(zb.y - tv[5], 0.f); p[5] = d*d;
        d = fmaxf(zb.z - tv[6], 0.f); p[6] = d*d;
        d = fmaxf(zb.w - tv[7], 0.f); p[7] = d*d;
        #pragma unroll
        for (int n = 0; n < 8; ++n) {
            acc[n][0] = fmaf(p[n], kvv.x, acc[n][0]);
            acc[n][1] = fmaf(p[n], kvv.y, acc[n][1]);
            acc[n][2] = fmaf(p[n], kvv.z, acc[n][2]);
            acc[n][3] = fmaf(p[n], kvv.w, acc[n][3]);
        }
    }
    // cross-wave reduce via LDS
    __shared__ float redls[4*NHEADS*HIDDEN];    // 32 KB
    float4* red4 = (float4*)redls;
    #pragma unroll
    for (int n = 0; n < 8; ++n) {
        float4 v; v.x = acc[n][0]; v.y = acc[n][1]; v.z = acc[n][2]; v.w = acc[n][3];
        red4[((size_t)wave*8 + n)*64 + lane] = v;
    }
    __syncthreads();
    float* up = upart + ((size_t)mb*NCHUNK + chunk)*NHEADS*HIDDEN;
    int n = t >> 5, hq = (t & 31)*2;
    #pragma unroll
    for (int j = 0; j < 2; ++j) {
        float4 s = red4[((size_t)0*8 + n)*64 + hq + j];
        #pragma unroll
        for (int w = 1; w < 4; ++w) {
            float4 v = red4[((size_t)w*8 + n)*64 + hq + j];
            s.x += v.x; s.y += v.y; s.z += v.z; s.w += v.w;
        }
        ((float4*)(up + (size_t)n*HIDDEN))[hq + j] = s;
    }
}

// K5: reduce chunks, project through Wv, apply modality softmax weight
__global__ void k_ctx(const float* __restrict__ upart, const float* __restrict__ Wv0,
                      const float* __restrict__ Wv1, const float* __restrict__ mlogits,
                      float* __restrict__ comb) {
    int b = blockIdx.x, t = threadIdx.x;
    __shared__ float ul[NHEADS*260];
    float l0 = mlogits[0], l1 = mlogits[1];
    float mxl = fmaxf(l0, l1);
    float e0 = __expf(l0 - mxl), e1 = __expf(l1 - mxl);
    float w0 = e0/(e0 + e1), w1 = e1/(e0 + e1);
    for (int m = 0; m < 2; ++m) {
        const float* Wv = m ? Wv1 : Wv0;
        float wm = m ? w1 : w0;
        __syncthreads();
        for (int n = 0; n < NHEADS; ++n) {
            float s = 0.f;
            const float* up = upart + ((size_t)m*BATCH + b)*NCHUNK*NHEADS*HIDDEN
                              + (size_t)n*HIDDEN + t;
            #pragma unroll
            for (int c = 0; c < NCHUNK; ++c) s += up[(size_t)c*NHEADS*HIDDEN];
            ul[n*260 + t] = s;
        }
        __syncthreads();
        int n = t >> 5;   // t = n*32 + d
        const float4* wr4 = (const float4*)(Wv + (size_t)t*HIDDEN);
        const float4* uu4 = (const float4*)(ul + n*260);
        float acc = 0.f;
        #pragma unroll 8
        for (int i = 0; i < HIDDEN/4; ++i) {
            float4 w = wr4[i], uu = uu4[i];
            acc += w.x*uu.x + w.y*uu.y + w.z*uu.z + w.w*uu.w;
        }
        comb[(size_t)b*(2*HIDDEN) + (size_t)m*HIDDEN + t] = acc * wm;
    }
}

// K6: out = LayerNorm(comb @ Wout^T + b_out + z_gene)
__global__ void k_out(const float* __restrict__ comb, const float* __restrict__ Wout,
                      const float* __restrict__ bout, const float* __restrict__ zg,
                      const float* __restrict__ gamma, const float* __restrict__ beta,
                      float* __restrict__ out) {
    int b = blockIdx.x, t = threadIdx.x;
    __shared__ float cl[2*HIDDEN];
    __shared__ float red[4];
    cl[t] = comb[(size_t)b*512 + t];
    cl[t + 256] = comb[(size_t)b*512 + 256 + t];
    __syncthreads();
    float acc = bout[t] + zg[(size_t)b*HIDDEN + t];
    const float4* wr4 = (const float4*)(Wout + (size_t)t*512);
    const float4* cl4 = (const float4*)cl;
    #pragma unroll 8
    for (int i = 0; i < 512/4; ++i) {
        float4 w = wr4[i], c = cl4[i];
        acc += w.x*c.x + w.y*c.y + w.z*c.z + w.w*c.w;
    }
    float s = acc;
    for (int off = 32; off; off >>= 1) s += __shfl_xor(s, off);
    if ((t & 63) == 0) red[t >> 6] = s;
    __syncthreads();
    float mu = (red[0] + red[1] + red[2] + red[3]) * (1.0f/HIDDEN);
    __syncthreads();
    float dv = acc - mu;
    float vs = dv*dv;
    for (int off = 32; off; off >>= 1) vs += __shfl_xor(vs, off);
    if ((t & 63) == 0) red[t >> 6] = vs;
    __syncthreads();
    float var = (red[0] + red[1] + red[2] + red[3]) * (1.0f/HIDDEN);
    out[(size_t)b*HIDDEN + t] = dv * rsqrtf(var + LN_EPS) * gamma[t] + beta[t];
}

extern "C" void kernel_launch(void* const* d_in, const int* in_sizes, int n_in,
                              void* d_out, int out_size, void* d_ws, size_t ws_size,
                              hipStream_t stream) {
    const float* zg    = (const float*)d_in[0];
    const float* cpg   = (const float*)d_in[1];
    const float* mir   = (const float*)d_in[2];
    const float* Wq    = (const float*)d_in[3];
    const float* Wk0   = (const float*)d_in[4];
    const float* Wv0   = (const float*)d_in[5];
    const float* Wk1   = (const float*)d_in[6];
    const float* Wv1   = (const float*)d_in[7];
    const float* Wout  = (const float*)d_in[8];
    const float* bout  = (const float*)d_in[9];
    const float* gam   = (const float*)d_in[10];
    const float* bet   = (const float*)d_in[11];
    const float* mlog  = (const float*)d_in[12];
    const float* ltemp = (const float*)d_in[13];

    float* ws   = (float*)d_ws;
    float* qt   = ws + OFF_QT;
    float* sc   = ws + OFF_SC;
    float* tau  = ws + OFF_TAU;
    float* up   = ws + OFF_UP;
    float* comb = ws + OFF_COMB;
    float* out  = (float*)d_out;

    hipLaunchKernelGGL(k_prep,   dim3(BATCH),           dim3(256), 0, stream,
                       zg, Wq, Wk0, Wk1, ltemp, qt);
    hipLaunchKernelGGL(k_scores, dim3(2*BATCH*NSLAB),   dim3(256), 0, stream,
                       cpg, mir, qt, sc);
    hipLaunchKernelGGL(k_entmax, dim3(2*BATCH*NHEADS),  dim3(256), 0, stream,
                       sc, tau);
    hipLaunchKernelGGL(k_ctxsum, dim3(2*BATCH*NCHUNK),  dim3(256), 0, stream,
                       cpg, mir, sc, tau, up);
    hipLaunchKernelGGL(k_ctx,    dim3(BATCH),           dim3(256), 0, stream,
                       up, Wv0, Wv1, mlog, comb);
    hipLaunchKernelGGL(k_out,    dim3(BATCH),           dim3(256), 0, stream,
                       comb, Wout, bout, zg, gam, bet, out);
}